// Round 1
// baseline (62.368 us; speedup 1.0000x reference)
//
#include <hip/hip_runtime.h>

// Problem constants (match reference)
#define T_LEN   4096
#define NKNOT   6          // KNOT+2
#define NSEG    5          // KNOT+1
#define STEP    819        // (T_LEN-1)/(KNOT+1) == 4095/5, exact integer
#define B_SZ    128
#define C_CH    32
#define P_THR   0.5f

// ---------------------------------------------------------------------------
// Solve the 6x6 not-a-knot second-derivative system: A * S2 = R  (double prec)
// ---------------------------------------------------------------------------
__device__ void solve_S2(double S2[NKNOT][NKNOT]) {
    double A[NKNOT][NKNOT], R[NKNOT][NKNOT];
    for (int i = 0; i < NKNOT; ++i)
        for (int j = 0; j < NKNOT; ++j) { A[i][j] = 0.0; R[i][j] = 0.0; }
    const double h = (double)STEP;
    // interior rows (uniform spacing: 2*(h+h) = 4h)
    for (int i = 1; i <= NKNOT - 2; ++i) {
        A[i][i-1] = h;      A[i][i] = 4.0 * h;   A[i][i+1] = h;
        R[i][i-1] = 6.0/h;  R[i][i] = -12.0/h;   R[i][i+1] = 6.0/h;
    }
    // not-a-knot boundary rows (R rows are zero)
    A[0][0] = h;              A[0][1] = -2.0 * h;          A[0][2] = h;
    A[NKNOT-1][NKNOT-3] = h;  A[NKNOT-1][NKNOT-2] = -2.0*h; A[NKNOT-1][NKNOT-1] = h;
    // Gauss-Jordan with partial pivoting
    for (int col = 0; col < NKNOT; ++col) {
        int piv = col;
        for (int r = col + 1; r < NKNOT; ++r)
            if (fabs(A[r][col]) > fabs(A[piv][col])) piv = r;
        if (piv != col) {
            for (int k = 0; k < NKNOT; ++k) {
                double t = A[col][k]; A[col][k] = A[piv][k]; A[piv][k] = t;
                t = R[col][k]; R[col][k] = R[piv][k]; R[piv][k] = t;
            }
        }
        double d = 1.0 / A[col][col];
        for (int k = 0; k < NKNOT; ++k) { A[col][k] *= d; R[col][k] *= d; }
        for (int r = 0; r < NKNOT; ++r) {
            if (r == col) continue;
            double f = A[r][col];
            if (f != 0.0)
                for (int k = 0; k < NKNOT; ++k) {
                    A[r][k] -= f * A[col][k];
                    R[r][k] -= f * R[col][k];
                }
        }
    }
    for (int i = 0; i < NKNOT; ++i)
        for (int j = 0; j < NKNOT; ++j) S2[i][j] = R[i][j];
}

// ---------------------------------------------------------------------------
// Kernel 1: tabulate Bmat into d_ws as 6 planes of T_LEN floats ([k][t] layout)
// ---------------------------------------------------------------------------
__global__ __launch_bounds__(256) void build_bmat(float* __restrict__ bmat) {
    __shared__ double S2s[NKNOT][NKNOT];
    if (threadIdx.x == 0) {
        double S2[NKNOT][NKNOT];
        solve_S2(S2);
        for (int i = 0; i < NKNOT; ++i)
            for (int j = 0; j < NKNOT; ++j) S2s[i][j] = S2[i][j];
    }
    __syncthreads();
    const double h = (double)STEP;
    for (int t = threadIdx.x; t < T_LEN; t += blockDim.x) {
        int idx = t / STEP; if (idx > NSEG - 1) idx = NSEG - 1;
        double dl = (double)(t - idx * STEP);
        double dr = (double)((idx + 1) * STEP - t);
        #pragma unroll
        for (int k = 0; k < NKNOT; ++k) {
            double Si = S2s[idx][k], Sj = S2s[idx + 1][k];
            double Yi = (idx == k)     ? 1.0 : 0.0;
            double Yj = (idx + 1 == k) ? 1.0 : 0.0;
            double w = (Si * dr * dr * dr + Sj * dl * dl * dl) / (6.0 * h)
                     + (Yi - Si * h * h / 6.0) * dr / h
                     + (Yj - Sj * h * h / 6.0) * dl / h;
            bmat[k * T_LEN + t] = (float)w;
        }
    }
}

// ---------------------------------------------------------------------------
// Kernel 2: one block per (b,c); float4-vectorized over t using tabulated Bmat
// ---------------------------------------------------------------------------
__global__ __launch_bounds__(256) void magwarp_pre(
    const float* __restrict__ x, const float* __restrict__ yy,
    const float* __restrict__ mask_u, const float* __restrict__ bmat,
    float* __restrict__ out) {
    const int bc = blockIdx.x;           // 0 .. B_SZ*C_CH-1
    const int b  = bc >> 5;              // / C_CH
    const int c  = bc & (C_CH - 1);
    const bool apply = mask_u[b] < P_THR;

    float y[NKNOT];
    #pragma unroll
    for (int k = 0; k < NKNOT; ++k) y[k] = yy[(b * NKNOT + k) * C_CH + c];

    const float* xp = x   + (size_t)bc * T_LEN;
    float*       op = out + (size_t)bc * T_LEN;

    for (int t0 = threadIdx.x * 4; t0 < T_LEN; t0 += 256 * 4) {
        float4 xv = *(const float4*)(xp + t0);
        if (apply) {
            float4 cv = make_float4(0.f, 0.f, 0.f, 0.f);
            #pragma unroll
            for (int k = 0; k < NKNOT; ++k) {
                float4 wv = *(const float4*)(bmat + k * T_LEN + t0);
                cv.x += wv.x * y[k]; cv.y += wv.y * y[k];
                cv.z += wv.z * y[k]; cv.w += wv.w * y[k];
            }
            xv.x *= cv.x; xv.y *= cv.y; xv.z *= cv.z; xv.w *= cv.w;
        }
        *(float4*)(op + t0) = xv;
    }
}

// ---------------------------------------------------------------------------
// Fallback (ws too small): per-block S2 solve + inline basis evaluation
// ---------------------------------------------------------------------------
__global__ __launch_bounds__(256) void magwarp_fused(
    const float* __restrict__ x, const float* __restrict__ yy,
    const float* __restrict__ mask_u, float* __restrict__ out) {
    __shared__ float S2s[NKNOT][NKNOT];
    if (threadIdx.x == 0) {
        double S2[NKNOT][NKNOT];
        solve_S2(S2);
        for (int i = 0; i < NKNOT; ++i)
            for (int j = 0; j < NKNOT; ++j) S2s[i][j] = (float)S2[i][j];
    }
    __syncthreads();

    const int bc = blockIdx.x;
    const int b  = bc >> 5;
    const int c  = bc & (C_CH - 1);
    const bool apply = mask_u[b] < P_THR;

    float y[NKNOT];
    #pragma unroll
    for (int k = 0; k < NKNOT; ++k) y[k] = yy[(b * NKNOT + k) * C_CH + c];

    const float* xp = x   + (size_t)bc * T_LEN;
    float*       op = out + (size_t)bc * T_LEN;

    const float h     = (float)STEP;
    const float invh  = 1.0f / h;
    const float inv6h = 1.0f / (6.0f * h);
    const float h2_6  = h * h / 6.0f;

    for (int t0 = threadIdx.x * 4; t0 < T_LEN; t0 += 256 * 4) {
        float4 xv = *(const float4*)(xp + t0);
        if (apply) {
            float cr[4];
            #pragma unroll
            for (int j = 0; j < 4; ++j) {
                int t = t0 + j;
                int idx = t / STEP; if (idx > NSEG - 1) idx = NSEG - 1;
                float dl = (float)(t - idx * STEP);
                float dr = (float)((idx + 1) * STEP - t);
                float dl3 = dl * dl * dl, dr3 = dr * dr * dr;
                float acc = 0.f;
                #pragma unroll
                for (int k = 0; k < NKNOT; ++k) {
                    float Si = S2s[idx][k], Sj = S2s[idx + 1][k];
                    float Yi = (idx == k)     ? 1.f : 0.f;
                    float Yj = (idx + 1 == k) ? 1.f : 0.f;
                    float w = (Si * dr3 + Sj * dl3) * inv6h
                            + (Yi - Si * h2_6) * dr * invh
                            + (Yj - Sj * h2_6) * dl * invh;
                    acc += w * y[k];
                }
                cr[j] = acc;
            }
            xv.x *= cr[0]; xv.y *= cr[1]; xv.z *= cr[2]; xv.w *= cr[3];
        }
        *(float4*)(op + t0) = xv;
    }
}

// ---------------------------------------------------------------------------
extern "C" void kernel_launch(void* const* d_in, const int* in_sizes, int n_in,
                              void* d_out, int out_size, void* d_ws, size_t ws_size,
                              hipStream_t stream) {
    const float* x    = (const float*)d_in[0];   // (128, 32, 4096) f32
    const float* yy   = (const float*)d_in[1];   // (128, 6, 32)    f32
    const float* mu   = (const float*)d_in[2];   // (128, 1, 1)     f32
    float*       out  = (float*)d_out;

    const size_t bmat_bytes = (size_t)NKNOT * T_LEN * sizeof(float);
    const int nblocks = B_SZ * C_CH;             // 4096

    if (ws_size >= bmat_bytes) {
        float* bmat = (float*)d_ws;
        hipLaunchKernelGGL(build_bmat, dim3(1), dim3(256), 0, stream, bmat);
        hipLaunchKernelGGL(magwarp_pre, dim3(nblocks), dim3(256), 0, stream,
                           x, yy, mu, bmat, out);
    } else {
        hipLaunchKernelGGL(magwarp_fused, dim3(nblocks), dim3(256), 0, stream,
                           x, yy, mu, out);
    }
}

// Round 2
// 25.684 us; speedup vs baseline: 2.4282x; 2.4282x over previous
//
#include <hip/hip_runtime.h>

// Problem constants (match reference)
#define T_LEN   4096
#define NKNOT   6          // KNOT+2
#define NSEG    5          // KNOT+1
#define STEP    819        // (T_LEN-1)/(KNOT+1) == 4095/5, exact integer
#define B_SZ    128
#define C_CH    32
#define P_THR   0.5f

// ---------------------------------------------------------------------------
// Compile-time solve of the 6x6 not-a-knot system + per-segment basis coeffs.
// For segment s, basis weight of knot k at offset dl (dr = STEP - dl):
//   w_k = a[s][k]*dr^3 + b[s][k]*dl^3 + c[s][k]*dr + d[s][k]*dl
// so curve(t) = A*dr^3 + B*dl^3 + C*dr + D*dl with {A..D} = sum_k coef*y_k.
// ---------------------------------------------------------------------------
struct Coefs {
    float a[NSEG][NKNOT];
    float b[NSEG][NKNOT];
    float c[NSEG][NKNOT];
    float d[NSEG][NKNOT];
};

constexpr double cabs_(double x) { return x < 0.0 ? -x : x; }

constexpr Coefs compute_coefs() {
    double A[NKNOT][NKNOT] = {}, R[NKNOT][NKNOT] = {};
    const double h = (double)STEP;
    // interior continuity rows (uniform spacing)
    for (int i = 1; i <= NKNOT - 2; ++i) {
        A[i][i-1] = h;       A[i][i] = 4.0 * h;   A[i][i+1] = h;
        R[i][i-1] = 6.0/h;   R[i][i] = -12.0/h;   R[i][i+1] = 6.0/h;
    }
    // not-a-knot boundary rows (R rows zero)
    A[0][0] = h;              A[0][1] = -2.0*h;             A[0][2] = h;
    A[NKNOT-1][NKNOT-3] = h;  A[NKNOT-1][NKNOT-2] = -2.0*h; A[NKNOT-1][NKNOT-1] = h;
    // Gauss-Jordan with partial pivoting: R := A^-1 * R  (= S2)
    for (int col = 0; col < NKNOT; ++col) {
        int piv = col;
        for (int r = col + 1; r < NKNOT; ++r)
            if (cabs_(A[r][col]) > cabs_(A[piv][col])) piv = r;
        if (piv != col) {
            for (int k = 0; k < NKNOT; ++k) {
                double t = A[col][k]; A[col][k] = A[piv][k]; A[piv][k] = t;
                t = R[col][k]; R[col][k] = R[piv][k]; R[piv][k] = t;
            }
        }
        double dinv = 1.0 / A[col][col];
        for (int k = 0; k < NKNOT; ++k) { A[col][k] *= dinv; R[col][k] *= dinv; }
        for (int r = 0; r < NKNOT; ++r) {
            if (r == col) continue;
            double f = A[r][col];
            for (int k = 0; k < NKNOT; ++k) {
                A[r][k] -= f * A[col][k];
                R[r][k] -= f * R[col][k];
            }
        }
    }
    // R now holds S2 (second derivatives per unit y)
    Coefs out{};
    for (int s = 0; s < NSEG; ++s)
        for (int k = 0; k < NKNOT; ++k) {
            double Si = R[s][k], Sj = R[s+1][k];
            double Yi = (s == k)     ? 1.0 : 0.0;
            double Yj = (s + 1 == k) ? 1.0 : 0.0;
            out.a[s][k] = (float)(Si / (6.0 * h));
            out.b[s][k] = (float)(Sj / (6.0 * h));
            out.c[s][k] = (float)((Yi - Si * h * h / 6.0) / h);
            out.d[s][k] = (float)((Yj - Sj * h * h / 6.0) / h);
        }
    return out;
}

__device__ constexpr Coefs COEF = compute_coefs();

// ---------------------------------------------------------------------------
// Single fused kernel: one block per (b,c). Threads 0..4 fold yy into the
// 5-segment cubic coefficient table in LDS; then float4-vectorized t-loop.
// ---------------------------------------------------------------------------
__global__ __launch_bounds__(256) void magwarp(
    const float* __restrict__ x, const float* __restrict__ yy,
    const float* __restrict__ mask_u, float* __restrict__ out) {
    const int bc = blockIdx.x;            // 0 .. B_SZ*C_CH-1
    const int b  = bc >> 5;               // / C_CH
    const int c  = bc & (C_CH - 1);
    const bool apply = mask_u[b] < P_THR;

    __shared__ float4 cs[NSEG];           // {A,B,C,D} per segment
    if (apply && threadIdx.x < NSEG) {
        const int s = threadIdx.x;
        float A = 0.f, B = 0.f, C = 0.f, D = 0.f;
        #pragma unroll
        for (int k = 0; k < NKNOT; ++k) {
            float y = yy[(b * NKNOT + k) * C_CH + c];
            A += COEF.a[s][k] * y;
            B += COEF.b[s][k] * y;
            C += COEF.c[s][k] * y;
            D += COEF.d[s][k] * y;
        }
        cs[s] = make_float4(A, B, C, D);
    }
    __syncthreads();

    const size_t base = (size_t)bc * T_LEN;
    const float* xp = x   + base;
    float*       op = out + base;

    if (!apply) {
        #pragma unroll
        for (int it = 0; it < T_LEN / (256 * 4); ++it) {
            const int t0 = threadIdx.x * 4 + it * 256 * 4;
            *(float4*)(op + t0) = *(const float4*)(xp + t0);
        }
        return;
    }

    #pragma unroll
    for (int it = 0; it < T_LEN / (256 * 4); ++it) {
        const int t0 = threadIdx.x * 4 + it * 256 * 4;
        float4 xv = *(const float4*)(xp + t0);
        float r[4];
        #pragma unroll
        for (int j = 0; j < 4; ++j) {
            const int t = t0 + j;
            int seg = t / STEP;                       // magic-mul, no divide
            seg = seg > NSEG - 1 ? NSEG - 1 : seg;
            const float dl = (float)(t - seg * STEP);
            const float dr = (float)STEP - dl;
            const float4 cf = cs[seg];                // ds_read_b128, broadcast
            const float dl3 = dl * dl * dl;
            const float dr3 = dr * dr * dr;
            r[j] = cf.x * dr3 + cf.y * dl3 + cf.z * dr + cf.w * dl;
        }
        xv.x *= r[0]; xv.y *= r[1]; xv.z *= r[2]; xv.w *= r[3];
        *(float4*)(op + t0) = xv;
    }
}

// ---------------------------------------------------------------------------
extern "C" void kernel_launch(void* const* d_in, const int* in_sizes, int n_in,
                              void* d_out, int out_size, void* d_ws, size_t ws_size,
                              hipStream_t stream) {
    const float* x   = (const float*)d_in[0];   // (128, 32, 4096) f32
    const float* yy  = (const float*)d_in[1];   // (128, 6, 32)    f32
    const float* mu  = (const float*)d_in[2];   // (128, 1, 1)     f32
    float*       out = (float*)d_out;

    const int nblocks = B_SZ * C_CH;            // 4096
    hipLaunchKernelGGL(magwarp, dim3(nblocks), dim3(256), 0, stream,
                       x, yy, mu, out);
}